// Round 8
// baseline (8312.648 us; speedup 1.0000x reference)
//
#include <hip/hip_runtime.h>
#include <math.h>

#define B    32
#define H    1024
#define EMB  512
#define V    32000
#define SOS  1

// ws float offsets. x/h layout: [k][b], b contiguous.
#define OFF_X   0            // EMB*B = 16384
#define OFF_HA  16384        // H*B
#define OFF_HB  49152        // H*B
#define OFF_P   81920        // float4[500][32] = 64000 floats
#define OFF_C   145920       // [T][B] = 2048
#define OFF_CNT 147968       // T ints

#define NEG_INF (-3.0e38f)

typedef float f4v __attribute__((ext_vector_type(4)));

__device__ __forceinline__ void sm_merge(float& m, float& l, int& a,
                                         float om, float ol, int oa)
{
    const bool take = (om > m) || (om == m && oa < a);
    const float mn = take ? om : m;
    const int   an = take ? oa : a;
    l = l * expf(m - mn) + ol * expf(om - mn);
    m = mn; a = an;
}

// ---------------------------------------------------------------- INIT
__global__ void k_init(const float* __restrict__ ih, const float* __restrict__ emb,
                       float* __restrict__ ws, int T)
{
    int idx = blockIdx.x * blockDim.x + threadIdx.x;
    int stride = gridDim.x * blockDim.x;
    for (int i = idx; i < EMB * B; i += stride)
        ws[OFF_X + i] = tanhf(emb[(size_t)SOS * EMB + (i >> 5)]);
    for (int i = idx; i < H * B; i += stride) {
        int j = i >> 5, b = i & 31;
        ws[OFF_HA + j * 32 + b] = ih[(size_t)b * H + j];
    }
    int* cnt = (int*)(ws + OFF_CNT);
    for (int i = idx; i < T; i += stride) cnt[i] = 0;
}

// ---------------------------------------------------------------- GRU (256 blocks x 1024) — proven body
__global__ __launch_bounds__(1024) void k_gru(
    const float* __restrict__ xG, const float* __restrict__ hold,
    const float* __restrict__ wih, const float* __restrict__ bih,
    const float* __restrict__ whh, const float* __restrict__ bhh,
    float* __restrict__ hnew)
{
    const int t   = threadIdx.x;
    const int blk = blockIdx.x;
    __shared__ float sred[4 * 1152];

    const int ks = t >> 7;
    const int pl = t & 127;
    const int p  = blk * 128 + pl;
    const int b  = p & 31;
    const int j  = p >> 5;

    float ar = 0.f, az = 0.f, ain = 0.f, ahn = 0.f;
    const int k0 = ks * 192, k1 = k0 + 192;

    const int xe = (k1 < EMB) ? k1 : EMB;
    for (int k = k0; k < xe; k += 4) {
        const float u0 = xG[(k + 0) * 32 + b];
        const float u1 = xG[(k + 1) * 32 + b];
        const float u2 = xG[(k + 2) * 32 + b];
        const float u3 = xG[(k + 3) * 32 + b];
        const float4 w0 = *(const float4*)&wih[(size_t)(0 * H + j) * EMB + k];
        const float4 w1 = *(const float4*)&wih[(size_t)(1 * H + j) * EMB + k];
        const float4 w2 = *(const float4*)&wih[(size_t)(2 * H + j) * EMB + k];
        ar  = fmaf(w0.x, u0, fmaf(w0.y, u1, fmaf(w0.z, u2, fmaf(w0.w, u3, ar))));
        az  = fmaf(w1.x, u0, fmaf(w1.y, u1, fmaf(w1.z, u2, fmaf(w1.w, u3, az))));
        ain = fmaf(w2.x, u0, fmaf(w2.y, u1, fmaf(w2.z, u2, fmaf(w2.w, u3, ain))));
    }
    const int hs = (k0 > EMB) ? k0 : EMB;
    for (int k = hs; k < k1; k += 4) {
        const int kh = k - EMB;
        const float u0 = hold[(kh + 0) * 32 + b];
        const float u1 = hold[(kh + 1) * 32 + b];
        const float u2 = hold[(kh + 2) * 32 + b];
        const float u3 = hold[(kh + 3) * 32 + b];
        const float4 w0 = *(const float4*)&whh[(size_t)(0 * H + j) * H + kh];
        const float4 w1 = *(const float4*)&whh[(size_t)(1 * H + j) * H + kh];
        const float4 w2 = *(const float4*)&whh[(size_t)(2 * H + j) * H + kh];
        ar  = fmaf(w0.x, u0, fmaf(w0.y, u1, fmaf(w0.z, u2, fmaf(w0.w, u3, ar))));
        az  = fmaf(w1.x, u0, fmaf(w1.y, u1, fmaf(w1.z, u2, fmaf(w1.w, u3, az))));
        ahn = fmaf(w2.x, u0, fmaf(w2.y, u1, fmaf(w2.z, u2, fmaf(w2.w, u3, ahn))));
    }

    sred[0 * 1152 + pl * 9 + ks] = ar;
    sred[1 * 1152 + pl * 9 + ks] = az;
    sred[2 * 1152 + pl * 9 + ks] = ain;
    sred[3 * 1152 + pl * 9 + ks] = ahn;
    __syncthreads();

    if (t < 128) {
        const int pp = blk * 128 + t;
        const int bb = pp & 31, jj = pp >> 5;
        float s0 = 0.f, s1 = 0.f, s2 = 0.f, s3 = 0.f;
#pragma unroll
        for (int q = 0; q < 8; ++q) {
            s0 += sred[0 * 1152 + t * 9 + q];
            s1 += sred[1 * 1152 + t * 9 + q];
            s2 += sred[2 * 1152 + t * 9 + q];
            s3 += sred[3 * 1152 + t * 9 + q];
        }
        float gr  = s0 + bih[jj]         + bhh[jj];
        float gz  = s1 + bih[H + jj]     + bhh[H + jj];
        float gin = s2 + bih[2 * H + jj];
        float ghn = s3 + bhh[2 * H + jj];
        float r = 1.f / (1.f + expf(-gr));
        float z = 1.f / (1.f + expf(-gz));
        float n = tanhf(gin + r * ghn);   // r multiplies hh-part only
        const int hidx = jj * 32 + bb;
        hnew[hidx] = (1.f - z) * n + z * hold[hidx];
    }
}

// ---------------------------------------------------------------- PROJ (+ FIN fused)
// 500 blocks x 256 thr (4 waves). Tile 64 rows x 32 b.
// wave = bg (8 b's); lane: s = l&7 (k-eighth of chunk), rg = l>>3; R=8 rows (rg+8i), C=8 b.
// LDS: W [2][64][36] (pad), h-chunk transposed [2][32 b][36]. No cross-wave reduce (shfl butterfly).
#define WBUF 2304           // 64*36
#define HBUF 1152           // 32*36

__global__ __launch_bounds__(256, 2) void k_proj(
    const float* __restrict__ h, const float* __restrict__ wout,
    const float* __restrict__ bout, float* __restrict__ orow,
    float4* __restrict__ P, int* __restrict__ cnt,
    const float* __restrict__ emb, float* __restrict__ xG, float* __restrict__ C)
{
    __shared__ __align__(16) float Wl[2 * WBUF];
    __shared__ __align__(16) float Hl[2 * HBUF];
    __shared__ float cm[8][32], cl[8][32];
    __shared__ int   ca[8][32], stok[32], s_old;

    const int t   = threadIdx.x;
    const int blk = blockIdx.x;
    const int r0  = blk * 64;

    const int bg = t >> 6;          // wave id: b-octet
    const int l  = t & 63;
    const int s  = l & 7;           // k-eighth within chunk
    const int rg = l >> 3;          // 0..7; rows rg+8i

    // W staging: row sr, quads sq,sq+1
    const int sr = t >> 2;
    const int sq = (t & 3) * 2;
    const float* gW = wout + (size_t)(r0 + sr) * H + sq * 4;
    const int lW = sr * 36 + sq * 4;
    // h staging: k = hk, b = hb4..hb4+3 (transpose into [b][k])
    const int hk  = t >> 3;
    const int hb4 = (t & 7) * 4;

    float acc[8][8];
#pragma unroll
    for (int i = 0; i < 8; ++i)
#pragma unroll
        for (int j = 0; j < 8; ++j) acc[i][j] = 0.f;

    // prologue: stage chunk 0 into buf 0
    {
        const float4 w0 = *(const float4*)&gW[0];
        const float4 w1 = *(const float4*)&gW[4];
        *(float4*)&Wl[lW]     = w0;
        *(float4*)&Wl[lW + 4] = w1;
        const float4 hv = *(const float4*)&h[(size_t)hk * 32 + hb4];
        Hl[(hb4 + 0) * 36 + hk] = hv.x;
        Hl[(hb4 + 1) * 36 + hk] = hv.y;
        Hl[(hb4 + 2) * 36 + hk] = hv.z;
        Hl[(hb4 + 3) * 36 + hk] = hv.w;
    }
    __syncthreads();

    for (int c = 0; c < 32; ++c) {
        const int cur = c & 1;
        float4 pw0, pw1, ph;
        if (c + 1 < 32) {
            pw0 = *(const float4*)&gW[(c + 1) * 32];
            pw1 = *(const float4*)&gW[(c + 1) * 32 + 4];
            ph  = *(const float4*)&h[(size_t)((c + 1) * 32 + hk) * 32 + hb4];
        }
        const float* wb = Wl + cur * WBUF;
        const float* hb = Hl + cur * HBUF;

        float4 hv[8];
#pragma unroll
        for (int jj = 0; jj < 8; ++jj)
            hv[jj] = *(const float4*)&hb[(bg * 8 + jj) * 36 + s * 4];
#pragma unroll
        for (int i = 0; i < 8; ++i) {
            const float4 wv = *(const float4*)&wb[(rg + 8 * i) * 36 + s * 4];
#pragma unroll
            for (int jj = 0; jj < 8; ++jj) {
                acc[i][jj] = fmaf(wv.x, hv[jj].x, acc[i][jj]);
                acc[i][jj] = fmaf(wv.y, hv[jj].y, acc[i][jj]);
                acc[i][jj] = fmaf(wv.z, hv[jj].z, acc[i][jj]);
                acc[i][jj] = fmaf(wv.w, hv[jj].w, acc[i][jj]);
            }
        }
        if (c + 1 < 32) {
            float* wn = Wl + (cur ^ 1) * WBUF;
            float* hn = Hl + (cur ^ 1) * HBUF;
            *(float4*)&wn[lW]     = pw0;
            *(float4*)&wn[lW + 4] = pw1;
            hn[(hb4 + 0) * 36 + hk] = ph.x;
            hn[(hb4 + 1) * 36 + hk] = ph.y;
            hn[(hb4 + 2) * 36 + hk] = ph.z;
            hn[(hb4 + 3) * 36 + hk] = ph.w;
        }
        __syncthreads();
    }

    // butterfly k-reduce over s (lane bits 0-2)
#pragma unroll
    for (int i = 0; i < 8; ++i)
#pragma unroll
        for (int jj = 0; jj < 8; ++jj) {
            acc[i][jj] += __shfl_xor(acc[i][jj], 1);
            acc[i][jj] += __shfl_xor(acc[i][jj], 2);
            acc[i][jj] += __shfl_xor(acc[i][jj], 4);
        }

    // bias
#pragma unroll
    for (int i = 0; i < 8; ++i) {
        const float bo = bout[r0 + rg + 8 * i];
#pragma unroll
        for (int jj = 0; jj < 8; ++jj) acc[i][jj] += bo;
    }

    // coalesced logit stores: lane (rg,s) stores row rg+8s (compile-time select)
    {
        float outv[8];
#pragma unroll
        for (int i = 0; i < 8; ++i) {
            if (s == i) {
#pragma unroll
                for (int jj = 0; jj < 8; ++jj) outv[jj] = acc[i][jj];
            }
        }
        const int row = r0 + rg + 8 * s;
#pragma unroll
        for (int jj = 0; jj < 8; ++jj)
            __builtin_nontemporal_store(outv[jj], &orow[(size_t)(bg * 8 + jj) * V + row]);
    }

    // FIN1: online (m, sum-exp, argmax) over this lane's 8 rows, then over rg
    {
        float m[8], ll[8]; int a[8];
#pragma unroll
        for (int jj = 0; jj < 8; ++jj) {
            m[jj] = acc[0][jj]; a[jj] = r0 + rg; ll[jj] = 1.0f;
#pragma unroll
            for (int i = 1; i < 8; ++i) {
                const float x = acc[i][jj];
                if (x > m[jj]) {
                    ll[jj] = ll[jj] * expf(m[jj] - x) + 1.0f;
                    m[jj] = x; a[jj] = r0 + rg + 8 * i;
                } else {
                    ll[jj] += expf(x - m[jj]);
                }
            }
        }
#pragma unroll
        for (int mk = 8; mk <= 32; mk <<= 1) {
#pragma unroll
            for (int jj = 0; jj < 8; ++jj)
                sm_merge(m[jj], ll[jj], a[jj],
                         __shfl_xor(m[jj], mk), __shfl_xor(ll[jj], mk),
                         __shfl_xor(a[jj], mk));
        }
        if (l == 0) {
#pragma unroll
            for (int jj = 0; jj < 8; ++jj)
                P[blk * 32 + bg * 8 + jj] = make_float4(m[jj], ll[jj], (float)a[jj], 0.f);
        }
    }

    // last-block FIN2
    __syncthreads();
    if (t == 0) { __threadfence(); s_old = atomicAdd(cnt, 1); }
    __syncthreads();
    if (s_old == 499) {
        __threadfence();
        const int b = t & 31, seg = t >> 5;
        float m = NEG_INF, lsum = 0.f; int a = 0x7FFFFFFF;
        for (int e = seg; e < 500; e += 8) {
            const float4 p = P[e * 32 + b];
            sm_merge(m, lsum, a, p.x, p.y, (int)p.z);
        }
        cm[seg][b] = m; cl[seg][b] = lsum; ca[seg][b] = a;
        __syncthreads();
        if (seg == 0) {
#pragma unroll
            for (int q = 1; q < 8; ++q) sm_merge(m, lsum, a, cm[q][b], cl[q][b], ca[q][b]);
            C[b] = m + logf(lsum);
            stok[b] = a;
        }
        __syncthreads();
        const int TOK = stok[b];
        for (int k = seg; k < EMB; k += 8)
            xG[k * 32 + b] = tanhf(emb[(size_t)TOK * EMB + k]);
    }
}

// ---------------------------------------------------------------- deferred subtract
__global__ __launch_bounds__(256) void k_sub(float* __restrict__ out,
                                             const float* __restrict__ C)
{
    const int r = blockIdx.x;
    const float c = C[r];
    f4v* row = (f4v*)(out + (size_t)r * V);
    for (int v = threadIdx.x; v < V / 4; v += 256) {
        f4v x = __builtin_nontemporal_load(&row[v]);
        x -= c;
        __builtin_nontemporal_store(x, &row[v]);
    }
}

// ---------------------------------------------------------------- launch
extern "C" void kernel_launch(void* const* d_in, const int* in_sizes, int n_in,
                              void* d_out, int out_size, void* d_ws, size_t ws_size,
                              hipStream_t stream)
{
    const float* p_ih   = (const float*)d_in[0];
    // d_in[1] encoder_outputs unused; d_in[2] tgt_len recovered from out_size
    const float* p_emb  = (const float*)d_in[3];
    const float* p_wih  = (const float*)d_in[4];
    const float* p_bih  = (const float*)d_in[5];
    const float* p_whh  = (const float*)d_in[6];
    const float* p_bhh  = (const float*)d_in[7];
    const float* p_wout = (const float*)d_in[8];
    const float* p_bout = (const float*)d_in[9];
    float* out = (float*)d_out;
    float* ws  = (float*)d_ws;
    const int T = out_size / (B * V);

    float*  xG  = ws + OFF_X;
    float*  hA  = ws + OFF_HA;
    float*  hB  = ws + OFF_HB;
    float4* P   = (float4*)(ws + OFF_P);
    float*  C   = ws + OFF_C;
    int*    cnt = (int*)(ws + OFF_CNT);

    k_init<<<64, 256, 0, stream>>>(p_ih, p_emb, ws, T);

    for (int st = 0; st < T; ++st) {
        float* hold = (st & 1) ? hB : hA;
        float* hnew = (st & 1) ? hA : hB;
        float* orow = out + (size_t)st * B * V;
        k_gru<<<256, 1024, 0, stream>>>(xG, hold, p_wih, p_bih, p_whh, p_bhh, hnew);
        k_proj<<<500, 256, 0, stream>>>(hnew, p_wout, p_bout, orow, P, cnt + st,
                                        p_emb, xG, C + st * B);
    }
    k_sub<<<T * B, 256, 0, stream>>>(out, C);
}

// Round 9
// 6021.490 us; speedup vs baseline: 1.3805x; 1.3805x over previous
//
#include <hip/hip_runtime.h>
#include <math.h>

#define B    32
#define H    1024
#define EMB  512
#define V    32000
#define SOS  1

// ws float offsets. h layout: [j][b], b contiguous.
#define OFF_HA 0            // H*B = 32768
#define OFF_HB 32768        // H*B
#define OFF_P  65536        // float4[500][32] = 64000 floats
#define OFF_C  129536       // [T][B]

#define NEG_INF (-3.0e38f)

typedef float f4v __attribute__((ext_vector_type(4)));

__device__ __forceinline__ void sm_merge(float& m, float& l, int& a,
                                         float om, float ol, int oa)
{
    const bool take = (om > m) || (om == m && oa < a);
    const float mn = take ? om : m;
    const int   an = take ? oa : a;
    l = l * expf(m - mn) + ol * expf(om - mn);
    m = mn; a = an;
}

// ---------------------------------------------------------------- INIT
__global__ void k_init(const float* __restrict__ ih, float* __restrict__ ws)
{
    int idx = blockIdx.x * blockDim.x + threadIdx.x;
    int stride = gridDim.x * blockDim.x;
    for (int i = idx; i < H * B; i += stride) {
        int j = i >> 5, b = i & 31;
        ws[OFF_HA + j * 32 + b] = ih[(size_t)b * H + j];
    }
}

// ---------------------------------------------------------------- GRU (+ fused FIN2 of previous step)
// 256 blocks x 1024. Phase A: every block redundantly reduces P[500][32] -> TOK[32]
// (block 0 also writes C of the previous step). Phase B: x = tanh(emb[TOK]) staged
// to LDS [512][33]. Phase C: round-7 GRU body (x from LDS, h from global).
#define XL_F  (512 * 33)                    // 16896 floats
#define DSMG  ((XL_F + 4 * 1152) * 4)       // + sred = 86016 B

__global__ __launch_bounds__(1024) void k_gru(
    const float4* __restrict__ P, const float* __restrict__ emb,
    const float* __restrict__ hold,
    const float* __restrict__ wih, const float* __restrict__ bih,
    const float* __restrict__ whh, const float* __restrict__ bhh,
    float* __restrict__ hnew, float* __restrict__ C_prev, int first)
{
    extern __shared__ __align__(16) float dsm[];
    float* xl   = dsm;              // [512][33]
    float* sred = dsm + XL_F;       // [4][1152]
    __shared__ int stok_s[32];

    const int t   = threadIdx.x;
    const int blk = blockIdx.x;

    // ---------- Phase A: FIN2 of previous step (redundant per block)
    if (first) {
        if (t < 32) stok_s[t] = SOS;
    } else {
        float* fm = dsm;                    // [32][33] (aliased, pre-xl)
        float* fl = dsm + 1056;
        int*   fa = (int*)(dsm + 2112);
        const int seg = t >> 5, b = t & 31;
        float m = NEG_INF, l = 0.f; int a = 0x7FFFFFFF;
        for (int e = seg; e < 500; e += 32) {
            const float4 p = P[e * 32 + b];
            sm_merge(m, l, a, p.x, p.y, (int)p.z);
        }
        fm[seg * 33 + b] = m; fl[seg * 33 + b] = l; fa[seg * 33 + b] = a;
        __syncthreads();
        for (int s2 = 16; s2 > 0; s2 >>= 1) {
            if (t < s2 * 32) {
                const int sg = t >> 5, bb = t & 31;
                float mm = fm[sg * 33 + bb]; float ll = fl[sg * 33 + bb];
                int aa = fa[sg * 33 + bb];
                sm_merge(mm, ll, aa, fm[(sg + s2) * 33 + bb],
                         fl[(sg + s2) * 33 + bb], fa[(sg + s2) * 33 + bb]);
                fm[sg * 33 + bb] = mm; fl[sg * 33 + bb] = ll; fa[sg * 33 + bb] = aa;
            }
            __syncthreads();
        }
        if (t < 32) {
            stok_s[t] = fa[t];
            if (blk == 0) C_prev[t] = fm[t] + logf(fl[t]);
        }
    }
    __syncthreads();

    // ---------- Phase B: stage x = tanh(emb[TOK]) into LDS
    {
        const int b = t & 31;
        const int TOK = stok_s[b];
        const int kq0 = t >> 5;             // 0..31
#pragma unroll
        for (int it = 0; it < 4; ++it) {
            const int kq = kq0 + 32 * it;   // 0..127
            const float4 e4 = *(const float4*)&emb[(size_t)TOK * EMB + kq * 4];
            xl[(4 * kq + 0) * 33 + b] = tanhf(e4.x);
            xl[(4 * kq + 1) * 33 + b] = tanhf(e4.y);
            xl[(4 * kq + 2) * 33 + b] = tanhf(e4.z);
            xl[(4 * kq + 3) * 33 + b] = tanhf(e4.w);
        }
    }
    __syncthreads();

    // ---------- Phase C: GRU (round-7 body; x from LDS)
    const int ks = t >> 7;
    const int pl = t & 127;
    const int p  = blk * 128 + pl;
    const int b  = p & 31;
    const int j  = p >> 5;

    float ar = 0.f, az = 0.f, ain = 0.f, ahn = 0.f;
    const int k0 = ks * 192, k1 = k0 + 192;

    const int xe = (k1 < EMB) ? k1 : EMB;
    for (int k = k0; k < xe; k += 4) {
        const float u0 = xl[(k + 0) * 33 + b];
        const float u1 = xl[(k + 1) * 33 + b];
        const float u2 = xl[(k + 2) * 33 + b];
        const float u3 = xl[(k + 3) * 33 + b];
        const float4 w0 = *(const float4*)&wih[(size_t)(0 * H + j) * EMB + k];
        const float4 w1 = *(const float4*)&wih[(size_t)(1 * H + j) * EMB + k];
        const float4 w2 = *(const float4*)&wih[(size_t)(2 * H + j) * EMB + k];
        ar  = fmaf(w0.x, u0, fmaf(w0.y, u1, fmaf(w0.z, u2, fmaf(w0.w, u3, ar))));
        az  = fmaf(w1.x, u0, fmaf(w1.y, u1, fmaf(w1.z, u2, fmaf(w1.w, u3, az))));
        ain = fmaf(w2.x, u0, fmaf(w2.y, u1, fmaf(w2.z, u2, fmaf(w2.w, u3, ain))));
    }
    const int hs = (k0 > EMB) ? k0 : EMB;
    for (int k = hs; k < k1; k += 4) {
        const int kh = k - EMB;
        const float u0 = hold[(kh + 0) * 32 + b];
        const float u1 = hold[(kh + 1) * 32 + b];
        const float u2 = hold[(kh + 2) * 32 + b];
        const float u3 = hold[(kh + 3) * 32 + b];
        const float4 w0 = *(const float4*)&whh[(size_t)(0 * H + j) * H + kh];
        const float4 w1 = *(const float4*)&whh[(size_t)(1 * H + j) * H + kh];
        const float4 w2 = *(const float4*)&whh[(size_t)(2 * H + j) * H + kh];
        ar  = fmaf(w0.x, u0, fmaf(w0.y, u1, fmaf(w0.z, u2, fmaf(w0.w, u3, ar))));
        az  = fmaf(w1.x, u0, fmaf(w1.y, u1, fmaf(w1.z, u2, fmaf(w1.w, u3, az))));
        ahn = fmaf(w2.x, u0, fmaf(w2.y, u1, fmaf(w2.z, u2, fmaf(w2.w, u3, ahn))));
    }

    sred[0 * 1152 + pl * 9 + ks] = ar;
    sred[1 * 1152 + pl * 9 + ks] = az;
    sred[2 * 1152 + pl * 9 + ks] = ain;
    sred[3 * 1152 + pl * 9 + ks] = ahn;
    __syncthreads();

    if (t < 128) {
        const int pp = blk * 128 + t;
        const int bb = pp & 31, jj = pp >> 5;
        float s0 = 0.f, s1 = 0.f, s2 = 0.f, s3 = 0.f;
#pragma unroll
        for (int q = 0; q < 8; ++q) {
            s0 += sred[0 * 1152 + t * 9 + q];
            s1 += sred[1 * 1152 + t * 9 + q];
            s2 += sred[2 * 1152 + t * 9 + q];
            s3 += sred[3 * 1152 + t * 9 + q];
        }
        float gr  = s0 + bih[jj]         + bhh[jj];
        float gz  = s1 + bih[H + jj]     + bhh[H + jj];
        float gin = s2 + bih[2 * H + jj];
        float ghn = s3 + bhh[2 * H + jj];
        float r = 1.f / (1.f + expf(-gr));
        float z = 1.f / (1.f + expf(-gz));
        float n = tanhf(gin + r * ghn);   // r multiplies hh-part only
        const int hidx = jj * 32 + bb;
        hnew[hidx] = (1.f - z) * n + z * hold[hidx];
    }
}

// ---------------------------------------------------------------- PROJ (exact round-7 body)
// 250 blocks x 512 thr; tile 128 rows x 32 b; thread (rg16,bg4,ks8): R=8,C=8, 4k/chunk.
#define PW  (128 * 36)
#define DSMP ((2 * PW + 2 * 1024 + 256 * 68) * 4)   // 114688 B

__global__ __launch_bounds__(512, 2) void k_proj(
    const float* __restrict__ h, const float* __restrict__ wout,
    const float* __restrict__ bout, float* __restrict__ orow,
    float4* __restrict__ partial)
{
    extern __shared__ __align__(16) float dsm[];
    float* Wl  = dsm;               // [2][PW]
    float* Hl  = dsm + 2 * PW;      // [2][1024]
    float* Red = Hl + 2048;         // [256][68]

    const int t   = threadIdx.x;
    const int blk = blockIdx.x;
    const int r0  = blk * 128;

    const int bg = t & 3;
    const int rg = (t >> 2) & 15;
    const int ks = t >> 6;

    const int srow = t >> 2;
    const int sq   = (t & 3) * 2;
    const float* gWp = wout + (size_t)(r0 + srow) * H + sq * 4;
    const int lW = srow * 36 + sq * 4;
    const int hk = t >> 3, hb = (t & 7) * 4;

    float acc[8][8];
#pragma unroll
    for (int i = 0; i < 8; ++i)
#pragma unroll
        for (int j = 0; j < 8; ++j) acc[i][j] = 0.f;

    {
        float4 w0 = *(const float4*)&gWp[0];
        float4 w1 = *(const float4*)&gWp[4];
        *(float4*)&Wl[lW] = w0;
        *(float4*)&Wl[lW + 4] = w1;
        if (t < 256) {
            float4 hv = *(const float4*)&h[hk * 32 + hb];
            *(float4*)&Hl[hk * 32 + hb] = hv;
        }
    }
    __syncthreads();

    for (int c = 0; c < 32; ++c) {
        const int cur = c & 1;
        float4 pw0, pw1, ph;
        if (c + 1 < 32) {
            pw0 = *(const float4*)&gWp[(c + 1) * 32];
            pw1 = *(const float4*)&gWp[(c + 1) * 32 + 4];
            if (t < 256) ph = *(const float4*)&h[(c + 1) * 1024 + hk * 32 + hb];
        }
        const float* wb = Wl + cur * PW;
        const float* hc = Hl + cur * 1024;

        float4 hv[4][2];
#pragma unroll
        for (int j = 0; j < 4; ++j) {
            hv[j][0] = *(const float4*)&hc[(ks * 4 + j) * 32 + bg * 8];
            hv[j][1] = *(const float4*)&hc[(ks * 4 + j) * 32 + bg * 8 + 4];
        }
#pragma unroll
        for (int i = 0; i < 8; ++i) {
            const int r = rg + 16 * i;
            const float4 wv = *(const float4*)&wb[r * 36 + ks * 4];
#pragma unroll
            for (int j = 0; j < 4; ++j) {
                const float wf = (j == 0) ? wv.x : (j == 1) ? wv.y : (j == 2) ? wv.z : wv.w;
                acc[i][0] = fmaf(wf, hv[j][0].x, acc[i][0]);
                acc[i][1] = fmaf(wf, hv[j][0].y, acc[i][1]);
                acc[i][2] = fmaf(wf, hv[j][0].z, acc[i][2]);
                acc[i][3] = fmaf(wf, hv[j][0].w, acc[i][3]);
                acc[i][4] = fmaf(wf, hv[j][1].x, acc[i][4]);
                acc[i][5] = fmaf(wf, hv[j][1].y, acc[i][5]);
                acc[i][6] = fmaf(wf, hv[j][1].z, acc[i][6]);
                acc[i][7] = fmaf(wf, hv[j][1].w, acc[i][7]);
            }
        }
        if (c + 1 < 32) {
            float* wn = Wl + (cur ^ 1) * PW;
            *(float4*)&wn[lW] = pw0;
            *(float4*)&wn[lW + 4] = pw1;
            if (t < 256) *(float4*)&Hl[(cur ^ 1) * 1024 + hk * 32 + hb] = ph;
        }
        __syncthreads();
    }

#define RED_ST(slot)                                                          \
    {                                                                         \
        float* rp = Red + (slot) * 68;                                        \
        _Pragma("unroll")                                                     \
        for (int i = 0; i < 8; ++i) {                                         \
            *(float4*)&rp[i * 8]     = make_float4(acc[i][0], acc[i][1], acc[i][2], acc[i][3]); \
            *(float4*)&rp[i * 8 + 4] = make_float4(acc[i][4], acc[i][5], acc[i][6], acc[i][7]); \
        }                                                                     \
    }
#define RED_ADD()                                                             \
    {                                                                         \
        const float* rp = Red + t * 68;                                       \
        _Pragma("unroll")                                                     \
        for (int i = 0; i < 8; ++i) {                                         \
            const float4 a0 = *(const float4*)&rp[i * 8];                     \
            const float4 a1 = *(const float4*)&rp[i * 8 + 4];                 \
            acc[i][0] += a0.x; acc[i][1] += a0.y; acc[i][2] += a0.z; acc[i][3] += a0.w; \
            acc[i][4] += a1.x; acc[i][5] += a1.y; acc[i][6] += a1.z; acc[i][7] += a1.w; \
        }                                                                     \
    }

    if (ks >= 4) RED_ST(t - 256);
    __syncthreads();
    if (ks < 4) RED_ADD();
    __syncthreads();
    if (ks == 2 || ks == 3) RED_ST(t - 128);
    __syncthreads();
    if (ks < 2) RED_ADD();
    __syncthreads();
    if (ks == 1) RED_ST(t - 64);
    __syncthreads();

    if (ks == 0) {
        RED_ADD();
#pragma unroll
        for (int i = 0; i < 8; ++i) {
            const int r = r0 + rg + 16 * i;
            const float bo = bout[r];
#pragma unroll
            for (int j = 0; j < 8; ++j) {
                acc[i][j] += bo;
                __builtin_nontemporal_store(acc[i][j],
                    &orow[(size_t)(bg * 8 + j) * V + r]);
            }
        }
        float m[8], l[8]; int a[8];
#pragma unroll
        for (int j = 0; j < 8; ++j) {
            m[j] = acc[0][j]; a[j] = r0 + rg; l[j] = 1.0f;
#pragma unroll
            for (int i = 1; i < 8; ++i) {
                const float x = acc[i][j];
                if (x > m[j]) {
                    l[j] = l[j] * expf(m[j] - x) + 1.0f;
                    m[j] = x; a[j] = r0 + rg + 16 * i;
                } else {
                    l[j] += expf(x - m[j]);
                }
            }
        }
#pragma unroll
        for (int mk = 4; mk <= 32; mk <<= 1) {
#pragma unroll
            for (int j = 0; j < 8; ++j) {
                const float om = __shfl_xor(m[j], mk);
                const float ol = __shfl_xor(l[j], mk);
                const int   oa = __shfl_xor(a[j], mk);
                const bool take = (om > m[j]) || (om == m[j] && oa < a[j]);
                const float mn = take ? om : m[j];
                const int   an = take ? oa : a[j];
                l[j] = l[j] * expf(m[j] - mn) + ol * expf(om - mn);
                m[j] = mn; a[j] = an;
            }
        }
        if (rg == 0) {
#pragma unroll
            for (int j = 0; j < 8; ++j)
                partial[blk * 32 + bg * 8 + j] = make_float4(m[j], l[j], (float)a[j], 0.f);
        }
    }
}

// ---------------------------------------------------------------- FINLAST: reduce last step's partials -> C
__global__ __launch_bounds__(1024) void k_finlast(
    const float4* __restrict__ P, float* __restrict__ C_last)
{
    __shared__ float fm[1056], fl[1056];
    __shared__ int   fa[1056];
    const int t = threadIdx.x;
    const int seg = t >> 5, b = t & 31;
    float m = NEG_INF, l = 0.f; int a = 0x7FFFFFFF;
    for (int e = seg; e < 500; e += 32) {
        const float4 p = P[e * 32 + b];
        sm_merge(m, l, a, p.x, p.y, (int)p.z);
    }
    fm[seg * 33 + b] = m; fl[seg * 33 + b] = l; fa[seg * 33 + b] = a;
    __syncthreads();
    for (int s2 = 16; s2 > 0; s2 >>= 1) {
        if (t < s2 * 32) {
            const int sg = t >> 5, bb = t & 31;
            float mm = fm[sg * 33 + bb]; float ll = fl[sg * 33 + bb];
            int aa = fa[sg * 33 + bb];
            sm_merge(mm, ll, aa, fm[(sg + s2) * 33 + bb],
                     fl[(sg + s2) * 33 + bb], fa[(sg + s2) * 33 + bb]);
            fm[sg * 33 + bb] = mm; fl[sg * 33 + bb] = ll; fa[sg * 33 + bb] = aa;
        }
        __syncthreads();
    }
    if (t < 32) C_last[t] = fm[t] + logf(fl[t]);
}

// ---------------------------------------------------------------- deferred subtract
__global__ __launch_bounds__(256) void k_sub(float* __restrict__ out,
                                             const float* __restrict__ C)
{
    const int r = blockIdx.x;
    const float c = C[r];
    f4v* row = (f4v*)(out + (size_t)r * V);
    for (int v = threadIdx.x; v < V / 4; v += 256) {
        f4v x = __builtin_nontemporal_load(&row[v]);
        x -= c;
        __builtin_nontemporal_store(x, &row[v]);
    }
}

// ---------------------------------------------------------------- launch
extern "C" void kernel_launch(void* const* d_in, const int* in_sizes, int n_in,
                              void* d_out, int out_size, void* d_ws, size_t ws_size,
                              hipStream_t stream)
{
    const float* p_ih   = (const float*)d_in[0];
    // d_in[1] encoder_outputs unused; d_in[2] tgt_len recovered from out_size
    const float* p_emb  = (const float*)d_in[3];
    const float* p_wih  = (const float*)d_in[4];
    const float* p_bih  = (const float*)d_in[5];
    const float* p_whh  = (const float*)d_in[6];
    const float* p_bhh  = (const float*)d_in[7];
    const float* p_wout = (const float*)d_in[8];
    const float* p_bout = (const float*)d_in[9];
    float* out = (float*)d_out;
    float* ws  = (float*)d_ws;
    const int T = out_size / (B * V);

    float*  hA = ws + OFF_HA;
    float*  hB = ws + OFF_HB;
    float4* P  = (float4*)(ws + OFF_P);
    float*  C  = ws + OFF_C;

    hipFuncSetAttribute((const void*)k_gru,
                        hipFuncAttributeMaxDynamicSharedMemorySize, DSMG);
    hipFuncSetAttribute((const void*)k_proj,
                        hipFuncAttributeMaxDynamicSharedMemorySize, DSMP);

    k_init<<<64, 256, 0, stream>>>(p_ih, ws);

    for (int st = 0; st < T; ++st) {
        float* hold = (st & 1) ? hB : hA;
        float* hnew = (st & 1) ? hA : hB;
        float* orow = out + (size_t)st * B * V;
        float* Cprv = C + (st > 0 ? (st - 1) * B : 0);
        k_gru<<<256, 1024, DSMG, stream>>>(P, p_emb, hold, p_wih, p_bih,
                                           p_whh, p_bhh, hnew, Cprv, st == 0 ? 1 : 0);
        k_proj<<<250, 512, DSMP, stream>>>(hnew, p_wout, p_bout, orow, P);
    }
    k_finlast<<<1, 1024, 0, stream>>>(P, C + (T - 1) * B);
    k_sub<<<T * B, 256, 0, stream>>>(out, C);
}

// Round 10
// 4049.570 us; speedup vs baseline: 2.0527x; 1.4869x over previous
//
#include <hip/hip_runtime.h>
#include <math.h>

#define B    32
#define H    1024
#define EMB  512
#define V    32000
#define SOS  1

// ws float offsets
#define OFF_X   0            // EMB*B
#define OFF_HA  16384        // H*B
#define OFF_HB  49152        // H*B
#define OFF_P   81920        // float4[250][32]
#define OFF_C   113920       // T*B
#define OFF_HHI 115968       // short[H*B]  (16384 floats)
#define OFF_HLO 132352       // short[H*B]
#define OFF_WHI 148736       // short[V*H]  (16384000 floats)
#define OFF_WLO 16532736     // short[V*H]

#define NEG_INF (-3.0e38f)

typedef float f4v   __attribute__((ext_vector_type(4)));
typedef short short8v __attribute__((ext_vector_type(8)));
typedef float f32x4 __attribute__((ext_vector_type(4)));

#define MF(a,b,c) c = __builtin_amdgcn_mfma_f32_16x16x32_bf16(a, b, c, 0, 0, 0)

__device__ __forceinline__ unsigned short rnb(float x) {
    unsigned u = __float_as_uint(x);
    unsigned r = u + 0x7FFFu + ((u >> 16) & 1u);
    return (unsigned short)(r >> 16);
}
__device__ __forceinline__ float bfh(unsigned short s) {
    return __uint_as_float(((unsigned)s) << 16);
}
__device__ __forceinline__ void sm_merge(float& m, float& l, int& a,
                                         float om, float ol, int oa)
{
    const bool take = (om > m) || (om == m && oa < a);
    const float mn = take ? om : m;
    const int   an = take ? oa : a;
    l = l * expf(m - mn) + ol * expf(om - mn);
    m = mn; a = an;
}

// ---------------------------------------------------------------- INIT (+ W hi/lo split)
__global__ void k_init(const float* __restrict__ ih, const float* __restrict__ emb,
                       const float* __restrict__ wout, float* __restrict__ ws)
{
    const size_t idx = (size_t)blockIdx.x * blockDim.x + threadIdx.x;
    const size_t stride = (size_t)gridDim.x * blockDim.x;
    for (size_t i = idx; i < EMB * B; i += stride)
        ws[OFF_X + i] = tanhf(emb[(size_t)SOS * EMB + (i >> 5)]);
    for (size_t i = idx; i < H * B; i += stride) {
        int j = (int)(i >> 5), b = (int)(i & 31);
        ws[OFF_HA + j * 32 + b] = ih[(size_t)b * H + j];
    }
    short* Whi = (short*)(ws + OFF_WHI);
    short* Wlo = (short*)(ws + OFF_WLO);
    for (size_t i = idx; i < (size_t)V * H; i += stride) {
        const float x = wout[i];
        const unsigned short hi = rnb(x);
        Whi[i] = (short)hi;
        Wlo[i] = (short)rnb(x - bfh(hi));
    }
}

// ---------------------------------------------------------------- GRU (R7 body + h hi/lo pack)
__global__ __launch_bounds__(1024) void k_gru(
    const float* __restrict__ xG, const float* __restrict__ hold,
    const float* __restrict__ wih, const float* __restrict__ bih,
    const float* __restrict__ whh, const float* __restrict__ bhh,
    float* __restrict__ hnew, short* __restrict__ Hhi, short* __restrict__ Hlo)
{
    const int t   = threadIdx.x;
    const int blk = blockIdx.x;
    __shared__ float sred[4 * 1152];

    const int ks = t >> 7;
    const int pl = t & 127;
    const int p  = blk * 128 + pl;
    const int b  = p & 31;
    const int j  = p >> 5;

    float ar = 0.f, az = 0.f, ain = 0.f, ahn = 0.f;
    const int k0 = ks * 192, k1 = k0 + 192;

    const int xe = (k1 < EMB) ? k1 : EMB;
    for (int k = k0; k < xe; k += 4) {
        const float u0 = xG[(k + 0) * 32 + b];
        const float u1 = xG[(k + 1) * 32 + b];
        const float u2 = xG[(k + 2) * 32 + b];
        const float u3 = xG[(k + 3) * 32 + b];
        const float4 w0 = *(const float4*)&wih[(size_t)(0 * H + j) * EMB + k];
        const float4 w1 = *(const float4*)&wih[(size_t)(1 * H + j) * EMB + k];
        const float4 w2 = *(const float4*)&wih[(size_t)(2 * H + j) * EMB + k];
        ar  = fmaf(w0.x, u0, fmaf(w0.y, u1, fmaf(w0.z, u2, fmaf(w0.w, u3, ar))));
        az  = fmaf(w1.x, u0, fmaf(w1.y, u1, fmaf(w1.z, u2, fmaf(w1.w, u3, az))));
        ain = fmaf(w2.x, u0, fmaf(w2.y, u1, fmaf(w2.z, u2, fmaf(w2.w, u3, ain))));
    }
    const int hs = (k0 > EMB) ? k0 : EMB;
    for (int k = hs; k < k1; k += 4) {
        const int kh = k - EMB;
        const float u0 = hold[(kh + 0) * 32 + b];
        const float u1 = hold[(kh + 1) * 32 + b];
        const float u2 = hold[(kh + 2) * 32 + b];
        const float u3 = hold[(kh + 3) * 32 + b];
        const float4 w0 = *(const float4*)&whh[(size_t)(0 * H + j) * H + kh];
        const float4 w1 = *(const float4*)&whh[(size_t)(1 * H + j) * H + kh];
        const float4 w2 = *(const float4*)&whh[(size_t)(2 * H + j) * H + kh];
        ar  = fmaf(w0.x, u0, fmaf(w0.y, u1, fmaf(w0.z, u2, fmaf(w0.w, u3, ar))));
        az  = fmaf(w1.x, u0, fmaf(w1.y, u1, fmaf(w1.z, u2, fmaf(w1.w, u3, az))));
        ahn = fmaf(w2.x, u0, fmaf(w2.y, u1, fmaf(w2.z, u2, fmaf(w2.w, u3, ahn))));
    }

    sred[0 * 1152 + pl * 9 + ks] = ar;
    sred[1 * 1152 + pl * 9 + ks] = az;
    sred[2 * 1152 + pl * 9 + ks] = ain;
    sred[3 * 1152 + pl * 9 + ks] = ahn;
    __syncthreads();

    if (t < 128) {
        const int pp = blk * 128 + t;
        const int bb = pp & 31, jj = pp >> 5;
        float s0 = 0.f, s1 = 0.f, s2 = 0.f, s3 = 0.f;
#pragma unroll
        for (int q = 0; q < 8; ++q) {
            s0 += sred[0 * 1152 + t * 9 + q];
            s1 += sred[1 * 1152 + t * 9 + q];
            s2 += sred[2 * 1152 + t * 9 + q];
            s3 += sred[3 * 1152 + t * 9 + q];
        }
        float gr  = s0 + bih[jj]         + bhh[jj];
        float gz  = s1 + bih[H + jj]     + bhh[H + jj];
        float gin = s2 + bih[2 * H + jj];
        float ghn = s3 + bhh[2 * H + jj];
        float r = 1.f / (1.f + expf(-gr));
        float z = 1.f / (1.f + expf(-gz));
        float n = tanhf(gin + r * ghn);   // r multiplies hh-part only
        const int hidx = jj * 32 + bb;
        const float hv = (1.f - z) * n + z * hold[hidx];
        hnew[hidx] = hv;
        // pack for MFMA B-fragments: layout [kq=jj>>3][b][jj&7]
        const unsigned short hi = rnb(hv);
        const unsigned short lo = rnb(hv - bfh(hi));
        const int pidx = (((jj >> 3) * 32) + bb) * 8 + (jj & 7);
        Hhi[pidx] = (short)hi;
        Hlo[pidx] = (short)lo;
    }
}

// ---------------------------------------------------------------- PROJ via bf16-MFMA (4-pass fp32 emulation)
// 250 blocks x 256 thr (4 waves). Block tile: 128 vocab rows x 32 b, K=1024.
// Wave w: rows [w*32, w*32+32) = 2 M-tiles; 32 b = 2 N-tiles. A: W hi/lo direct from
// global (streamed, no LDS). B: h hi/lo packed [kq][b][8], L1/L2-resident.
__global__ __launch_bounds__(256) void k_proj(
    const short* __restrict__ Whi, const short* __restrict__ Wlo,
    const short* __restrict__ Hhi, const short* __restrict__ Hlo,
    const float* __restrict__ bout, float* __restrict__ orow,
    float4* __restrict__ P)
{
    __shared__ float Dt[32 * 132];          // [b][row+pad] transpose for coalesced stores
    __shared__ float bl[128];
    __shared__ float pm[4][32], pls[4][32];
    __shared__ int   pa[4][32];

    const int t   = threadIdx.x;
    const int blk = blockIdx.x;
    const int r0  = blk * 128;
    const int w   = t >> 6;                 // wave 0..3
    const int l   = t & 63;
    const int lr  = l & 15;                 // row-in-tile / col-in-tile
    const int lg  = l >> 4;                 // k-group 0..3

    if (t < 128) bl[t] = bout[r0 + t];

    const short* pAh = Whi + (size_t)(r0 + w * 32 + lr) * H + lg * 8;
    const short* pAl = Wlo + (size_t)(r0 + w * 32 + lr) * H + lg * 8;
    const short* pBh = Hhi + (lg * 32 + lr) * 8;
    const short* pBl = Hlo + (lg * 32 + lr) * 8;

    f32x4 acc00 = {0.f, 0.f, 0.f, 0.f};
    f32x4 acc01 = {0.f, 0.f, 0.f, 0.f};
    f32x4 acc10 = {0.f, 0.f, 0.f, 0.f};
    f32x4 acc11 = {0.f, 0.f, 0.f, 0.f};

#pragma unroll 4
    for (int c = 0; c < 32; ++c) {
        const short8v a0h = *(const short8v*)(pAh + c * 32);
        const short8v a1h = *(const short8v*)(pAh + 16 * H + c * 32);
        const short8v a0l = *(const short8v*)(pAl + c * 32);
        const short8v a1l = *(const short8v*)(pAl + 16 * H + c * 32);
        const short8v b0h = *(const short8v*)(pBh + c * 1024);
        const short8v b1h = *(const short8v*)(pBh + c * 1024 + 128);
        const short8v b0l = *(const short8v*)(pBl + c * 1024);
        const short8v b1l = *(const short8v*)(pBl + c * 1024 + 128);
        MF(a0h, b0h, acc00); MF(a0h, b0l, acc00); MF(a0l, b0h, acc00); MF(a0l, b0l, acc00);
        MF(a0h, b1h, acc01); MF(a0h, b1l, acc01); MF(a0l, b1h, acc01); MF(a0l, b1l, acc01);
        MF(a1h, b0h, acc10); MF(a1h, b0l, acc10); MF(a1l, b0h, acc10); MF(a1l, b0l, acc10);
        MF(a1h, b1h, acc11); MF(a1h, b1l, acc11); MF(a1l, b1h, acc11); MF(a1l, b1l, acc11);
    }

    __syncthreads();   // bl ready; Dt free

    // bias + collect lane values: val[mt][nt][r], row = w*32 + mt*16 + 4*lg + r
    float val[2][2][4];
#pragma unroll
    for (int mt = 0; mt < 2; ++mt)
#pragma unroll
        for (int r = 0; r < 4; ++r) {
            const float bo = bl[w * 32 + mt * 16 + 4 * lg + r];
            val[mt][0][r] = (mt ? acc10[r] : acc00[r]) + bo;
            val[mt][1][r] = (mt ? acc11[r] : acc01[r]) + bo;
        }
#pragma unroll
    for (int mt = 0; mt < 2; ++mt)
#pragma unroll
        for (int nt = 0; nt < 2; ++nt)
#pragma unroll
            for (int r = 0; r < 4; ++r)
                Dt[(nt * 16 + lr) * 132 + w * 32 + mt * 16 + 4 * lg + r] = val[mt][nt][r];

    // FIN1: per-b online (m, sum-exp, argmax) over wave's 32 rows
#pragma unroll
    for (int nt = 0; nt < 2; ++nt) {
        float m = val[0][nt][0], lsum = 1.f;
        int   a = r0 + w * 32 + 4 * lg;
#pragma unroll
        for (int q = 1; q < 8; ++q) {
            const int mt = q >> 2, r = q & 3;
            const float x = val[mt][nt][r];
            const int row = r0 + w * 32 + mt * 16 + 4 * lg + r;
            if (x > m) { lsum = lsum * expf(m - x) + 1.f; m = x; a = row; }
            else       { lsum += expf(x - m); }
        }
        sm_merge(m, lsum, a, __shfl_xor(m, 16), __shfl_xor(lsum, 16), __shfl_xor(a, 16));
        sm_merge(m, lsum, a, __shfl_xor(m, 32), __shfl_xor(lsum, 32), __shfl_xor(a, 32));
        if (lg == 0) { pm[w][nt * 16 + lr] = m; pls[w][nt * 16 + lr] = lsum; pa[w][nt * 16 + lr] = a; }
    }
    __syncthreads();

    if (t < 32) {
        float m = pm[0][t], ls = pls[0][t]; int a = pa[0][t];
#pragma unroll
        for (int q = 1; q < 4; ++q) sm_merge(m, ls, a, pm[q][t], pls[q][t], pa[q][t]);
        P[blk * 32 + t] = make_float4(m, ls, (float)a, 0.f);
    }

    // coalesced nt-stores of raw logits: thread (b = t>>3, rq = t&7) covers 16 rows
    const int sb = t >> 3, rq = t & 7;
#pragma unroll
    for (int i = 0; i < 4; ++i) {
        const f4v v = *(const f4v*)&Dt[sb * 132 + rq * 16 + i * 4];
        __builtin_nontemporal_store(v, (f4v*)&orow[(size_t)sb * V + r0 + rq * 16 + i * 4]);
    }
}

// ---------------------------------------------------------------- FIN2 (R7): 250 partials -> TOK, C, xG
__global__ __launch_bounds__(256) void k_fin2(
    const float4* __restrict__ partial, const float* __restrict__ emb,
    float* __restrict__ xG, float* __restrict__ C)
{
    const int b = blockIdx.x;
    const int t = threadIdx.x;
    __shared__ float fm[256], fl[256];
    __shared__ int   fa[256], stok;

    float m = NEG_INF, l = 0.f; int a = 0x7FFFFFFF;
    if (t < 250) {
        float4 p = partial[t * 32 + b];
        m = p.x; l = p.y; a = (int)p.z;
    }
    fm[t] = m; fl[t] = l; fa[t] = a;
    __syncthreads();
    for (int s = 128; s > 0; s >>= 1) {
        if (t < s) {
            const float om = fm[t + s], ol = fl[t + s];
            const int   oa = fa[t + s];
            float mm = fm[t]; float ll = fl[t]; int aa = fa[t];
            const bool take = (om > mm) || (om == mm && oa < aa);
            const float mn = take ? om : mm;
            const int   an = take ? oa : aa;
            ll = ll * expf(mm - mn) + ol * expf(om - mn);
            fm[t] = mn; fl[t] = ll; fa[t] = an;
        }
        __syncthreads();
    }
    if (t == 0) {
        C[b] = fm[0] + logf(fl[0]);
        stok = fa[0];
    }
    __syncthreads();
    const int TOK = stok;
    for (int k = t; k < EMB; k += 256)
        xG[k * 32 + b] = tanhf(emb[(size_t)TOK * EMB + k]);
}

// ---------------------------------------------------------------- deferred subtract
__global__ __launch_bounds__(256) void k_sub(float* __restrict__ out,
                                             const float* __restrict__ C)
{
    const int r = blockIdx.x;
    const float c = C[r];
    f4v* row = (f4v*)(out + (size_t)r * V);
    for (int v = threadIdx.x; v < V / 4; v += 256) {
        f4v x = __builtin_nontemporal_load(&row[v]);
        x -= c;
        __builtin_nontemporal_store(x, &row[v]);
    }
}

// ---------------------------------------------------------------- launch
extern "C" void kernel_launch(void* const* d_in, const int* in_sizes, int n_in,
                              void* d_out, int out_size, void* d_ws, size_t ws_size,
                              hipStream_t stream)
{
    const float* p_ih   = (const float*)d_in[0];
    // d_in[1] encoder_outputs unused; d_in[2] tgt_len recovered from out_size
    const float* p_emb  = (const float*)d_in[3];
    const float* p_wih  = (const float*)d_in[4];
    const float* p_bih  = (const float*)d_in[5];
    const float* p_whh  = (const float*)d_in[6];
    const float* p_bhh  = (const float*)d_in[7];
    const float* p_wout = (const float*)d_in[8];
    const float* p_bout = (const float*)d_in[9];
    float* out = (float*)d_out;
    float* ws  = (float*)d_ws;
    const int T = out_size / (B * V);

    float*  xG  = ws + OFF_X;
    float*  hA  = ws + OFF_HA;
    float*  hB  = ws + OFF_HB;
    float4* P   = (float4*)(ws + OFF_P);
    float*  C   = ws + OFF_C;
    short*  Hhi = (short*)(ws + OFF_HHI);
    short*  Hlo = (short*)(ws + OFF_HLO);
    short*  Whi = (short*)(ws + OFF_WHI);
    short*  Wlo = (short*)(ws + OFF_WLO);

    k_init<<<2048, 256, 0, stream>>>(p_ih, p_emb, p_wout, ws);

    for (int st = 0; st < T; ++st) {
        float* hold = (st & 1) ? hB : hA;
        float* hnew = (st & 1) ? hA : hB;
        float* orow = out + (size_t)st * B * V;
        k_gru<<<256, 1024, 0, stream>>>(xG, hold, p_wih, p_bih, p_whh, p_bhh,
                                        hnew, Hhi, Hlo);
        k_proj<<<250, 256, 0, stream>>>(Whi, Wlo, Hhi, Hlo, p_bout, orow, P);
        k_fin2<<<B, 256, 0, stream>>>(P, p_emb, xG, C + st * B);
    }
    k_sub<<<T * B, 256, 0, stream>>>(out, C);
}